// Round 5
// baseline (233.381 us; speedup 1.0000x reference)
//
#include <hip/hip_runtime.h>

#define E_EDGES 131072
// Layer dims: in {2048,4096,4096} -> out {4096,4096,1024}, batch 1024.
// Activations feature-major (hT[feat][1024]); CSR-by-dst built on device;
// rows padded to multiples of 16 (zero-weight pads written by padfill_kernel).
// Scatter is XCD-local (group g = blockIdx&7 owns dst range g) and all
// streaming reads are NON-TEMPORAL so the scatter's dirty CSR region stays
// L2-resident and drains once as full lines (round-3 counters showed 4x
// write amplification from stream-induced eviction of partial lines).

#define EPAD01 196608   // capacity, layers 0,1 (4096 rows, E + 16*rows)
#define EPAD2  147456   // capacity, layer 2  (1024 rows)
#define SC_B   32       // scatter blocks per (layer, xcd-group)

#define NTL(p) __builtin_nontemporal_load(p)

// clang ext_vector: __builtin_nontemporal_load accepts vectors of int,
// unlike HIP's struct-wrapped int4.
typedef int iv4 __attribute__((ext_vector_type(4)));

__global__ void transpose_kernel(const float* __restrict__ in, float* __restrict__ out,
                                 int R, int C) {
  __shared__ float tile[32][33];
  int c0 = blockIdx.x << 5, r0 = blockIdx.y << 5;
  int tx = threadIdx.x, ty = threadIdx.y;  // 32 x 8
#pragma unroll
  for (int i = 0; i < 32; i += 8)
    tile[ty + i][tx] = in[(size_t)(r0 + ty + i) * C + (c0 + tx)];
  __syncthreads();
#pragma unroll
  for (int i = 0; i < 32; i += 8)
    out[(size_t)(c0 + ty + i) * R + (r0 + tx)] = tile[tx][ty + i];
}

// Histogram of dst for all 3 layers into cnt[3][4096].
__global__ void hist3_kernel(const int* __restrict__ d0, const int* __restrict__ d1,
                             const int* __restrict__ d2, int* __restrict__ cnt) {
  int i = blockIdx.x * blockDim.x + threadIdx.x;
  int l = i / E_EDGES, e = i - l * E_EDGES;  // l uniform per block
  const int* dp = (l == 0) ? d0 : (l == 1) ? d1 : d2;
  atomicAdd(&cnt[(l << 12) + NTL(dp + e)], 1);
}

// Exclusive scan of counts padded to multiples of 16 (blockIdx = layer).
// rowptr gets padded row starts; cnt is reset to row starts (scatter cursor).
__global__ void scan3_kernel(int* __restrict__ cnt, int* __restrict__ rowptr) {
  int l = blockIdx.x;
  int n = (l == 2) ? 1024 : 4096;
  int* c = cnt + (l << 12);
  int* rp = rowptr + l * 4104;
  int t = threadIdx.x;  // 1024 threads
  int k = n >> 10;      // 4 or 1 elements per thread
  int vals[4];
  int local = 0;
  for (int i = 0; i < k; ++i) {
    int v = (c[t * k + i] + 15) & ~15;  // pad row to multiple of 16
    vals[i] = v; local += v;
  }
  int lane = t & 63, wid = t >> 6;
  int incl = local;
  for (int off = 1; off < 64; off <<= 1) {
    int u = __shfl_up(incl, off, 64);
    if (lane >= off) incl += u;
  }
  __shared__ int wsum[16];
  if (lane == 63) wsum[wid] = incl;
  __syncthreads();
  if (t < 16) {
    int v = wsum[t];
    int iv = v;
    for (int off = 1; off < 16; off <<= 1) {
      int u = __shfl_up(iv, off, 16);
      if (t >= off) iv += u;
    }
    wsum[t] = iv - v;  // exclusive wave offset
  }
  __syncthreads();
  int run = wsum[wid] + (incl - local);
  for (int i = 0; i < k; ++i) { int v = vals[i]; rp[t * k + i] = run; c[t * k + i] = run; run += v; }
  if (t == 1023) rp[n] = run;
}

// XCD-local scatter: group g = blockIdx&7 owns dst rows [g*n/8,(g+1)*n/8).
// All stream reads non-temporal -> L2 keeps the dirty CSR region resident.
__global__ void __launch_bounds__(256) scatter3_kernel(
    const int* __restrict__ s0p, const int* __restrict__ d0p, const float* __restrict__ w0p,
    const int* __restrict__ s1p, const int* __restrict__ d1p, const float* __restrict__ w1p,
    const int* __restrict__ s2p, const int* __restrict__ d2p, const float* __restrict__ w2p,
    int* __restrict__ cursor, int2* __restrict__ edges) {
  int g = blockIdx.x & 7;
  int sub = blockIdx.x >> 3;        // [0, 3*SC_B)
  int l = sub / SC_B;
  int chunk = sub - l * SC_B;
  const int* sp = (l == 0) ? s0p : (l == 1) ? s1p : s2p;
  const int* dp = (l == 0) ? d0p : (l == 1) ? d1p : d2p;
  const float* wp = (l == 0) ? w0p : (l == 1) ? w1p : w2p;
  int off = (l == 0) ? 0 : (l == 1) ? EPAD01 : 2 * EPAD01;
  int shift = (l == 2) ? 7 : 9;     // dst range = n/8 = 128 or 512
  int base = chunk * (E_EDGES / SC_B);
  for (int k = 0; k < E_EDGES / SC_B; k += 256) {
    int e = base + k + threadIdx.x;
    int d = NTL(dp + e);
    if ((d >> shift) == g) {
      int s = NTL(sp + e);
      float wv = NTL(wp + e);
      int pos = atomicAdd(&cursor[(l << 12) + d], 1);
      edges[off + pos] = make_int2(s, __float_as_int(wv));
    }
  }
}

// Zero the pad slots [cursor[d], rowptr[d+1]) of every row (<= 15 per row).
__global__ void padfill_kernel(const int* __restrict__ cursor,
                               const int* __restrict__ rowptr,
                               int2* __restrict__ edges) {
  int i = blockIdx.x * 256 + threadIdx.x;   // 0..12287
  int l = i >> 12, d = i & 4095;
  if (l == 2 && d >= 1024) return;
  int off = (l == 0) ? 0 : (l == 1) ? EPAD01 : 2 * EPAD01;
  int end = rowptr[l * 4104 + d + 1];
  int2 z = make_int2(0, 0);
  for (int p = cursor[(l << 12) + d]; p < end; ++p) edges[off + p] = z;
}

#define LD2(IDX) (*(const float2*)(hb + ((size_t)(unsigned)(IDX) << 12)))
#define FMA2(A, WB, V) { float _w = __int_as_float(WB); \
  A.x = fmaf(_w, V.x, A.x); A.y = fmaf(_w, V.y, A.y); }

// SpMM gather: block = (dst row d, 128-col chunk c), 64 threads x 2 cols.
// c = blockIdx&7 -> chunk c on XCD c (2 MB input + 2 MB output slice resident
// in the 4 MB XCD L2; edge stream read non-temporally so it can't evict them).
__global__ void __launch_bounds__(64) spmm_kernel(const float* __restrict__ hT,
                                                  const int2* __restrict__ edges,
                                                  const int* __restrict__ rowptr,
                                                  const float* __restrict__ bias,
                                                  float* __restrict__ outT) {
  int c = blockIdx.x & 7;
  int d = blockIdx.x >> 3;
  int col = (c << 7) + (threadIdx.x << 1);
  const char* hb = (const char*)(hT + col);
  float2 a0 = {0, 0}, a1 = {0, 0}, a2 = {0, 0}, a3 = {0, 0};
  float2 a4 = {0, 0}, a5 = {0, 0}, a6 = {0, 0}, a7 = {0, 0};
  int s0 = rowptr[d], s1 = rowptr[d + 1];  // multiples of 16
  const iv4* ep = (const iv4*)(edges + s0);
  const iv4* ep_end = (const iv4*)(edges + s1);
  iv4 q0, q1, q2, q3, q4, q5, q6, q7;
  if (ep < ep_end) {
    q0 = NTL(ep + 0); q1 = NTL(ep + 1); q2 = NTL(ep + 2); q3 = NTL(ep + 3);
    q4 = NTL(ep + 4); q5 = NTL(ep + 5); q6 = NTL(ep + 6); q7 = NTL(ep + 7);
  }
  while (ep < ep_end) {
    iv4 p0 = q0, p1 = q1, p2 = q2, p3 = q3;
    iv4 p4 = q4, p5 = q5, p6 = q6, p7 = q7;
    ep += 8;
    if (ep < ep_end) {
      q0 = NTL(ep + 0); q1 = NTL(ep + 1); q2 = NTL(ep + 2); q3 = NTL(ep + 3);
      q4 = NTL(ep + 4); q5 = NTL(ep + 5); q6 = NTL(ep + 6); q7 = NTL(ep + 7);
    }
    float2 v0 = LD2(p0.x), v1 = LD2(p0.z), v2 = LD2(p1.x), v3 = LD2(p1.z);
    float2 v4 = LD2(p2.x), v5 = LD2(p2.z), v6 = LD2(p3.x), v7 = LD2(p3.z);
    float2 v8 = LD2(p4.x), v9 = LD2(p4.z), v10 = LD2(p5.x), v11 = LD2(p5.z);
    float2 v12 = LD2(p6.x), v13 = LD2(p6.z), v14 = LD2(p7.x), v15 = LD2(p7.z);
    FMA2(a0, p0.y, v0); FMA2(a1, p0.w, v1);
    FMA2(a2, p1.y, v2); FMA2(a3, p1.w, v3);
    FMA2(a4, p2.y, v4); FMA2(a5, p2.w, v5);
    FMA2(a6, p3.y, v6); FMA2(a7, p3.w, v7);
    FMA2(a0, p4.y, v8); FMA2(a1, p4.w, v9);
    FMA2(a2, p5.y, v10); FMA2(a3, p5.w, v11);
    FMA2(a4, p6.y, v12); FMA2(a5, p6.w, v13);
    FMA2(a6, p7.y, v14); FMA2(a7, p7.w, v15);
  }
  float b = bias[d];
  float rx = ((a0.x + a1.x) + (a2.x + a3.x)) + ((a4.x + a5.x) + (a6.x + a7.x));
  float ry = ((a0.y + a1.y) + (a2.y + a3.y)) + ((a4.y + a5.y) + (a6.y + a7.y));
  float2 o;
  o.x = fmaxf(rx + b, 0.f);
  o.y = fmaxf(ry + b, 0.f);
  *(float2*)((char*)outT + (((size_t)d << 12) + ((size_t)col << 2))) = o;
}

extern "C" void kernel_launch(void* const* d_in, const int* in_sizes, int n_in,
                              void* d_out, int out_size, void* d_ws, size_t ws_size,
                              hipStream_t stream) {
  const float* x = (const float*)d_in[0];
  const int* src[3]    = {(const int*)d_in[1], (const int*)d_in[5], (const int*)d_in[9]};
  const int* dst[3]    = {(const int*)d_in[2], (const int*)d_in[6], (const int*)d_in[10]};
  const float* w[3]    = {(const float*)d_in[3], (const float*)d_in[7], (const float*)d_in[11]};
  const float* bias[3] = {(const float*)d_in[4], (const float*)d_in[8], (const float*)d_in[12]};
  float* out = (float*)d_out;

  // Workspace (~36.5 MB):
  //   buf0 @ 0            : 16 MB (xT, later h2T)
  //   buf1 @ 16 MB        : 16 MB (h1T, later outT)
  //   cnt  @ 32 MB        : 12288 ints (histogram -> scatter cursor)
  //   rowptr @ 32M+64K    : 3*4104 ints
  //   edges  @ 32M+128K   : (2*EPAD01+EPAD2) int2, padded CSR
  char* ws = (char*)d_ws;
  float* buf0   = (float*)(ws);
  float* buf1   = (float*)(ws + (16u << 20));
  int*   cnt    = (int*)(ws + (32u << 20));
  int*   rowptr = (int*)(ws + (32u << 20) + 65536u);
  int2*  edges  = (int2*)(ws + (32u << 20) + 131072u);

  (void)hipMemsetAsync(cnt, 0, 12288 * sizeof(int), stream);

  dim3 tb(32, 8);
  // x [1024][2048] -> buf0 = xT [2048][1024]
  transpose_kernel<<<dim3(2048 / 32, 1024 / 32), tb, 0, stream>>>(x, buf0, 1024, 2048);

  hist3_kernel<<<(3 * E_EDGES) / 256, 256, 0, stream>>>(dst[0], dst[1], dst[2], cnt);
  scan3_kernel<<<3, 1024, 0, stream>>>(cnt, rowptr);
  scatter3_kernel<<<8 * 3 * SC_B, 256, 0, stream>>>(
      src[0], dst[0], w[0], src[1], dst[1], w[1], src[2], dst[2], w[2], cnt, edges);
  padfill_kernel<<<12288 / 256, 256, 0, stream>>>(cnt, rowptr, edges);

  // layer 0: buf0 (2048x1024) -> buf1 (4096x1024)
  spmm_kernel<<<4096 * 8, 64, 0, stream>>>(buf0, edges, rowptr, bias[0], buf1);
  // layer 1: buf1 -> buf0 (4096x1024)
  spmm_kernel<<<4096 * 8, 64, 0, stream>>>(buf1, edges + EPAD01, rowptr + 4104, bias[1], buf0);
  // layer 2: buf0 -> buf1 (1024x1024, outT)
  spmm_kernel<<<1024 * 8, 64, 0, stream>>>(buf0, edges + 2 * EPAD01, rowptr + 2 * 4104, bias[2], buf1);

  // outT [1024 dst][1024 batch] -> d_out [batch][dst]
  transpose_kernel<<<dim3(1024 / 32, 1024 / 32), tb, 0, stream>>>(buf1, out, 1024, 1024);
}

// Round 6
// 189.615 us; speedup vs baseline: 1.2308x; 1.2308x over previous
//
#include <hip/hip_runtime.h>

#define E_EDGES 131072
// Layer dims: in {2048,4096,4096} -> out {4096,4096,1024}, batch 1024.
// Activations feature-major (hT[feat][1024]); CSR-by-dst built on device with
// NO GLOBAL ATOMICS (round-5 post-mortem: device-scope atomicAdd cursor was
// a memory-side round trip per edge = 55 us). Three phases:
//   A) per-(layer,chunk) LDS histogram -> cntA[l][row][chunk]
//   B) scan: row totals, pad to 16, row scan -> rowptr/fillstart; cntA
//      rewritten in place as per-(row,chunk) start offsets
//   C) scatter: LDS cursor per block (init from cntA), LDS atomics only.
// Rows padded to multiples of 16 (zero pads written by padfill_kernel).

#define EPAD01 196608   // capacity, layers 0,1 (4096 rows, E + 16*rows)
#define EPAD2  147456   // capacity, layer 2  (1024 rows)
#define C_CH   16       // chunks per layer
#define CHUNK  (E_EDGES / C_CH)   // 8192 edges per chunk

#define NTL(p) __builtin_nontemporal_load(p)
typedef int iv4 __attribute__((ext_vector_type(4)));

__global__ void transpose_kernel(const float* __restrict__ in, float* __restrict__ out,
                                 int R, int C) {
  __shared__ float tile[32][33];
  int c0 = blockIdx.x << 5, r0 = blockIdx.y << 5;
  int tx = threadIdx.x, ty = threadIdx.y;  // 32 x 8
#pragma unroll
  for (int i = 0; i < 32; i += 8)
    tile[ty + i][tx] = in[(size_t)(r0 + ty + i) * C + (c0 + tx)];
  __syncthreads();
#pragma unroll
  for (int i = 0; i < 32; i += 8)
    out[(size_t)(c0 + ty + i) * R + (r0 + tx)] = tile[tx][ty + i];
}

// Phase A: per-(layer,chunk) LDS histogram of dst. bid = l*16 + c.
__global__ void __launch_bounds__(256) count_kernel(
    const int* __restrict__ d0, const int* __restrict__ d1, const int* __restrict__ d2,
    int* __restrict__ cntA) {
  int bid = blockIdx.x, l = bid >> 4, c = bid & 15;
  const int* dp = (l == 0) ? d0 : (l == 1) ? d1 : d2;
  __shared__ int hist[4096];
  for (int r = threadIdx.x; r < 4096; r += 256) hist[r] = 0;
  __syncthreads();
  int base = c * CHUNK;
  for (int i = 0; i < CHUNK; i += 256)
    atomicAdd(&hist[dp[base + i + threadIdx.x]], 1);
  __syncthreads();
  for (int r = threadIdx.x; r < 4096; r += 256)
    cntA[(((l << 12) + r) << 4) + c] = hist[r];  // layer2 rows>=1024 stay 0
}

// Phase B: per-layer (blockIdx = l) row totals -> padded row scan.
// rowptr[row] = padded row start; fillstart[row] = start + true count;
// cntA[row][c] rewritten to the chunk's start offset within the row.
__global__ void __launch_bounds__(1024) scan_kernel(int* __restrict__ cntA,
                                                    int* __restrict__ rowptr,
                                                    int* __restrict__ fillstart) {
  int l = blockIdx.x;
  int* rp = rowptr + l * 4104;
  int t = threadIdx.x;  // 1024 threads, 4 rows each
  int tot[4], pad[4];
  int local = 0;
  for (int i = 0; i < 4; ++i) {
    int row = (t << 2) + i;
    const int4* p = (const int4*)(cntA + (((l << 12) + row) << 4));
    int4 a = p[0], b = p[1], cc = p[2], dd = p[3];
    int s = a.x + a.y + a.z + a.w + b.x + b.y + b.z + b.w +
            cc.x + cc.y + cc.z + cc.w + dd.x + dd.y + dd.z + dd.w;
    tot[i] = s;
    pad[i] = (s + 15) & ~15;
    local += pad[i];
  }
  int lane = t & 63, wid = t >> 6;
  int incl = local;
  for (int off = 1; off < 64; off <<= 1) {
    int u = __shfl_up(incl, off, 64);
    if (lane >= off) incl += u;
  }
  __shared__ int wsum[16];
  if (lane == 63) wsum[wid] = incl;
  __syncthreads();
  if (t < 16) {
    int v = wsum[t];
    int iv = v;
    for (int off = 1; off < 16; off <<= 1) {
      int u = __shfl_up(iv, off, 16);
      if (t >= off) iv += u;
    }
    wsum[t] = iv - v;
  }
  __syncthreads();
  int run = wsum[wid] + (incl - local);
  for (int i = 0; i < 4; ++i) {
    int row = (t << 2) + i;
    rp[row] = run;
    fillstart[(l << 12) + row] = run + tot[i];
    int* p = cntA + (((l << 12) + row) << 4);
    int acc = run;
    for (int c = 0; c < 16; ++c) { int v = p[c]; p[c] = acc; acc += v; }
    run += pad[i];
  }
  if (t == 1023) rp[4096] = run;  // also covers rp[n] (rows past n are 0-count)
}

// Phase C: scatter with LDS cursors only. bid = l*16 + c.
__global__ void __launch_bounds__(256) scatter_kernel(
    const int* __restrict__ s0p, const int* __restrict__ d0p, const float* __restrict__ w0p,
    const int* __restrict__ s1p, const int* __restrict__ d1p, const float* __restrict__ w1p,
    const int* __restrict__ s2p, const int* __restrict__ d2p, const float* __restrict__ w2p,
    const int* __restrict__ cntA, int2* __restrict__ edges) {
  int bid = blockIdx.x, l = bid >> 4, c = bid & 15;
  const int* sp = (l == 0) ? s0p : (l == 1) ? s1p : s2p;
  const int* dp = (l == 0) ? d0p : (l == 1) ? d1p : d2p;
  const float* wp = (l == 0) ? w0p : (l == 1) ? w1p : w2p;
  int off = (l == 0) ? 0 : (l == 1) ? EPAD01 : 2 * EPAD01;
  __shared__ int cursor[4096];
  for (int r = threadIdx.x; r < 4096; r += 256)
    cursor[r] = cntA[(((l << 12) + r) << 4) + c];
  __syncthreads();
  int base = c * CHUNK;
  for (int i = 0; i < CHUNK; i += 256) {
    int e = base + i + threadIdx.x;
    int d = dp[e];
    int s = sp[e];
    float wv = wp[e];
    int pos = atomicAdd(&cursor[d], 1);
    edges[off + pos] = make_int2(s, __float_as_int(wv));
  }
}

// Zero the pad slots [fillstart[d], rowptr[d+1]) of every row (<= 15 per row).
__global__ void padfill_kernel(const int* __restrict__ fillstart,
                               const int* __restrict__ rowptr,
                               int2* __restrict__ edges) {
  int i = blockIdx.x * 256 + threadIdx.x;   // 0..12287
  int l = i >> 12, d = i & 4095;
  if (l == 2 && d >= 1024) return;
  int off = (l == 0) ? 0 : (l == 1) ? EPAD01 : 2 * EPAD01;
  int end = rowptr[l * 4104 + d + 1];
  int2 z = make_int2(0, 0);
  for (int p = fillstart[(l << 12) + d]; p < end; ++p) edges[off + p] = z;
}

#define LD2(IDX) (*(const float2*)(hb + ((size_t)(unsigned)(IDX) << 12)))
#define FMA2(A, WB, V) { float _w = __int_as_float(WB); \
  A.x = fmaf(_w, V.x, A.x); A.y = fmaf(_w, V.y, A.y); }

// SpMM gather: block = (dst row d, 128-col chunk c), 64 threads x 2 cols.
// c = blockIdx&7 -> chunk c on XCD c (2 MB input + 2 MB output slice resident
// in the 4 MB XCD L2; edge stream read non-temporally so it can't evict them).
__global__ void __launch_bounds__(64) spmm_kernel(const float* __restrict__ hT,
                                                  const int2* __restrict__ edges,
                                                  const int* __restrict__ rowptr,
                                                  const float* __restrict__ bias,
                                                  float* __restrict__ outT) {
  int c = blockIdx.x & 7;
  int d = blockIdx.x >> 3;
  int col = (c << 7) + (threadIdx.x << 1);
  const char* hb = (const char*)(hT + col);
  float2 a0 = {0, 0}, a1 = {0, 0}, a2 = {0, 0}, a3 = {0, 0};
  float2 a4 = {0, 0}, a5 = {0, 0}, a6 = {0, 0}, a7 = {0, 0};
  int s0 = rowptr[d], s1 = rowptr[d + 1];  // multiples of 16
  const iv4* ep = (const iv4*)(edges + s0);
  const iv4* ep_end = (const iv4*)(edges + s1);
  iv4 q0, q1, q2, q3, q4, q5, q6, q7;
  if (ep < ep_end) {
    q0 = NTL(ep + 0); q1 = NTL(ep + 1); q2 = NTL(ep + 2); q3 = NTL(ep + 3);
    q4 = NTL(ep + 4); q5 = NTL(ep + 5); q6 = NTL(ep + 6); q7 = NTL(ep + 7);
  }
  while (ep < ep_end) {
    iv4 p0 = q0, p1 = q1, p2 = q2, p3 = q3;
    iv4 p4 = q4, p5 = q5, p6 = q6, p7 = q7;
    ep += 8;
    if (ep < ep_end) {
      q0 = NTL(ep + 0); q1 = NTL(ep + 1); q2 = NTL(ep + 2); q3 = NTL(ep + 3);
      q4 = NTL(ep + 4); q5 = NTL(ep + 5); q6 = NTL(ep + 6); q7 = NTL(ep + 7);
    }
    float2 v0 = LD2(p0.x), v1 = LD2(p0.z), v2 = LD2(p1.x), v3 = LD2(p1.z);
    float2 v4 = LD2(p2.x), v5 = LD2(p2.z), v6 = LD2(p3.x), v7 = LD2(p3.z);
    float2 v8 = LD2(p4.x), v9 = LD2(p4.z), v10 = LD2(p5.x), v11 = LD2(p5.z);
    float2 v12 = LD2(p6.x), v13 = LD2(p6.z), v14 = LD2(p7.x), v15 = LD2(p7.z);
    FMA2(a0, p0.y, v0); FMA2(a1, p0.w, v1);
    FMA2(a2, p1.y, v2); FMA2(a3, p1.w, v3);
    FMA2(a4, p2.y, v4); FMA2(a5, p2.w, v5);
    FMA2(a6, p3.y, v6); FMA2(a7, p3.w, v7);
    FMA2(a0, p4.y, v8); FMA2(a1, p4.w, v9);
    FMA2(a2, p5.y, v10); FMA2(a3, p5.w, v11);
    FMA2(a4, p6.y, v12); FMA2(a5, p6.w, v13);
    FMA2(a6, p7.y, v14); FMA2(a7, p7.w, v15);
  }
  float b = bias[d];
  float rx = ((a0.x + a1.x) + (a2.x + a3.x)) + ((a4.x + a5.x) + (a6.x + a7.x));
  float ry = ((a0.y + a1.y) + (a2.y + a3.y)) + ((a4.y + a5.y) + (a6.y + a7.y));
  float2 o;
  o.x = fmaxf(rx + b, 0.f);
  o.y = fmaxf(ry + b, 0.f);
  *(float2*)((char*)outT + (((size_t)d << 12) + ((size_t)col << 2))) = o;
}

extern "C" void kernel_launch(void* const* d_in, const int* in_sizes, int n_in,
                              void* d_out, int out_size, void* d_ws, size_t ws_size,
                              hipStream_t stream) {
  const float* x = (const float*)d_in[0];
  const int* src[3]    = {(const int*)d_in[1], (const int*)d_in[5], (const int*)d_in[9]};
  const int* dst[3]    = {(const int*)d_in[2], (const int*)d_in[6], (const int*)d_in[10]};
  const float* w[3]    = {(const float*)d_in[3], (const float*)d_in[7], (const float*)d_in[11]};
  const float* bias[3] = {(const float*)d_in[4], (const float*)d_in[8], (const float*)d_in[12]};
  float* out = (float*)d_out;

  // Workspace (~37 MB):
  //   buf0 @ 0            : 16 MB (xT, later h2T)
  //   buf1 @ 16 MB        : 16 MB (h1T, later outT)
  //   fillstart @ 32 MB   : 3*4096 ints
  //   rowptr @ +64 KB     : 3*4104 ints
  //   cntA   @ +128 KB    : 3*4096*16 ints (per-(row,chunk) counts/offsets)
  //   edges  @ +1 MB      : (2*EPAD01+EPAD2) int2, padded CSR
  char* ws = (char*)d_ws;
  float* buf0      = (float*)(ws);
  float* buf1      = (float*)(ws + (16u << 20));
  int*   fillstart = (int*)(ws + (32u << 20));
  int*   rowptr    = (int*)(ws + (32u << 20) + 65536u);
  int*   cntA      = (int*)(ws + (32u << 20) + 131072u);
  int2*  edges     = (int2*)(ws + (32u << 20) + (1u << 20));

  dim3 tb(32, 8);
  // x [1024][2048] -> buf0 = xT [2048][1024]
  transpose_kernel<<<dim3(2048 / 32, 1024 / 32), tb, 0, stream>>>(x, buf0, 1024, 2048);

  count_kernel<<<3 * C_CH, 256, 0, stream>>>(dst[0], dst[1], dst[2], cntA);
  scan_kernel<<<3, 1024, 0, stream>>>(cntA, rowptr, fillstart);
  scatter_kernel<<<3 * C_CH, 256, 0, stream>>>(
      src[0], dst[0], w[0], src[1], dst[1], w[1], src[2], dst[2], w[2], cntA, edges);
  padfill_kernel<<<12288 / 256, 256, 0, stream>>>(fillstart, rowptr, edges);

  // layer 0: buf0 (2048x1024) -> buf1 (4096x1024)
  spmm_kernel<<<4096 * 8, 64, 0, stream>>>(buf0, edges, rowptr, bias[0], buf1);
  // layer 1: buf1 -> buf0 (4096x1024)
  spmm_kernel<<<4096 * 8, 64, 0, stream>>>(buf1, edges + EPAD01, rowptr + 4104, bias[1], buf0);
  // layer 2: buf0 -> buf1 (1024x1024, outT)
  spmm_kernel<<<1024 * 8, 64, 0, stream>>>(buf0, edges + 2 * EPAD01, rowptr + 2 * 4104, bias[2], buf1);

  // outT [1024 dst][1024 batch] -> d_out [batch][dst]
  transpose_kernel<<<dim3(1024 / 32, 1024 / 32), tb, 0, stream>>>(buf1, out, 1024, 1024);
}